// Round 2
// baseline (343.630 us; speedup 1.0000x reference)
//
#include <hip/hip_runtime.h>

#define BATCH   1048576
#define IN_DIM  64
#define OUT_DIM 16
#define GRID    2048
#define ITERS   8   // GRID * 64 rows/block * ITERS = 1048576

// ---------------------------------------------------------------------------
// Kernel 1: G = (A A^T)^-1  (16x16), C = G*A (16x64), written to workspace.
// Single block, 256 threads. Gauss-Jordan with partial pivoting in LDS.
// (unchanged from round 1 — validated)
// ---------------------------------------------------------------------------
__global__ __launch_bounds__(256) void precompute_kernel(
    const float* __restrict__ A, float* __restrict__ GC)
{
    __shared__ float sA[16][64];
    __shared__ float M[16][32];   // [S | I]
    __shared__ float fac[16];
    __shared__ int piv;

    const int tid = threadIdx.x;

    for (int i = tid; i < 1024; i += 256) sA[i >> 6][i & 63] = A[i];
    __syncthreads();

    {
        const int i = tid >> 4, j = tid & 15;
        float s = 0.f;
        #pragma unroll
        for (int k = 0; k < 64; ++k) s = fmaf(sA[i][k], sA[j][k], s);
        M[i][j] = s;
        M[i][16 + j] = (i == j) ? 1.f : 0.f;
    }
    __syncthreads();

    for (int p = 0; p < 16; ++p) {
        if (tid == 0) {
            int best = p;
            float bv = fabsf(M[p][p]);
            for (int r = p + 1; r < 16; ++r) {
                float v = fabsf(M[r][p]);
                if (v > bv) { bv = v; best = r; }
            }
            piv = best;
        }
        __syncthreads();
        if (tid < 32) {
            const int pr = piv;
            if (pr != p) { float t = M[p][tid]; M[p][tid] = M[pr][tid]; M[pr][tid] = t; }
        }
        __syncthreads();
        const float pv = M[p][p];
        __syncthreads();
        if (tid < 32) M[p][tid] *= (1.0f / pv);
        __syncthreads();
        if (tid < 16) fac[tid] = M[tid][p];
        __syncthreads();
        for (int e = tid; e < 512; e += 256) {
            const int r = e >> 5, c = e & 31;
            if (r != p) M[r][c] = fmaf(-fac[r], M[p][c], M[r][c]);
        }
        __syncthreads();
    }

    // G -> GC[0:256)
    {
        const int i = tid >> 4, j = tid & 15;
        GC[tid] = M[i][16 + j];
    }
    // C = G*A -> GC[256:1280)
    for (int e = tid; e < 1024; e += 256) {
        const int i = e >> 6, k = e & 63;
        float s = 0.f;
        #pragma unroll
        for (int j = 0; j < 16; ++j) s = fmaf(M[i][16 + j], sA[j][k], s);
        GC[256 + e] = s;
    }
}

// ---------------------------------------------------------------------------
// Kernel 2: x = y - C^T (A y - b).   4 lanes per row, 16 floats per lane.
// A and C staged in LDS as float4 rows (b128 broadcast reads, 2-way max).
// Quad shfl_xor butterfly for the 16-wide t-reduction.
// ---------------------------------------------------------------------------
__global__ __launch_bounds__(256) void apply_kernel(
    const float* __restrict__ y, const float* __restrict__ b,
    const float* __restrict__ A, const float* __restrict__ GC,
    float* __restrict__ out)
{
    __shared__ float4 sA4[256];   // A[j][k]: index j*16 + k/4
    __shared__ float4 sC4[256];   // C[j][k]: index j*16 + k/4

    const int tid = threadIdx.x;
    sA4[tid] = reinterpret_cast<const float4*>(A)[tid];
    sC4[tid] = reinterpret_cast<const float4*>(GC + 256)[tid];
    __syncthreads();

    const int c      = tid & 3;    // column-chunk: k in [c*16, c*16+16)
    const int rowInB = tid >> 2;   // 0..63

    for (int it = 0; it < ITERS; ++it) {
        const size_t row = ((size_t)blockIdx.x * ITERS + it) * 64 + rowInB;

        const float4* y4 = reinterpret_cast<const float4*>(y) + row * 16 + c * 4;
        const float4  bv = reinterpret_cast<const float4*>(b)[row * 4 + c];

        float4 yv0 = y4[0], yv1 = y4[1], yv2 = y4[2], yv3 = y4[3];

        // t[j] = partial dot of A-row j with this lane's 16 y values,
        // minus this lane's share of b.
        float t[16];
        #pragma unroll
        for (int j = 0; j < 16; ++j) {
            const float4 a0 = sA4[j * 16 + c * 4 + 0];
            const float4 a1 = sA4[j * 16 + c * 4 + 1];
            const float4 a2 = sA4[j * 16 + c * 4 + 2];
            const float4 a3 = sA4[j * 16 + c * 4 + 3];
            float acc;
            acc = a0.x * yv0.x;
            acc = fmaf(a0.y, yv0.y, acc);
            acc = fmaf(a0.z, yv0.z, acc);
            acc = fmaf(a0.w, yv0.w, acc);
            acc = fmaf(a1.x, yv1.x, acc);
            acc = fmaf(a1.y, yv1.y, acc);
            acc = fmaf(a1.z, yv1.z, acc);
            acc = fmaf(a1.w, yv1.w, acc);
            acc = fmaf(a2.x, yv2.x, acc);
            acc = fmaf(a2.y, yv2.y, acc);
            acc = fmaf(a2.z, yv2.z, acc);
            acc = fmaf(a2.w, yv2.w, acc);
            acc = fmaf(a3.x, yv3.x, acc);
            acc = fmaf(a3.y, yv3.y, acc);
            acc = fmaf(a3.z, yv3.z, acc);
            acc = fmaf(a3.w, yv3.w, acc);
            // fold -b: lane with c == j/4 owns b[j] (compile-time element pick)
            const float bb = ((j & 3) == 0) ? bv.x :
                             ((j & 3) == 1) ? bv.y :
                             ((j & 3) == 2) ? bv.z : bv.w;
            if (c == (j >> 2)) acc -= bb;
            t[j] = acc;
        }

        // quad butterfly: r = A y - b, full in all 4 lanes of the quad
        #pragma unroll
        for (int j = 0; j < 16; ++j) {
            t[j] += __shfl_xor(t[j], 1);
            t[j] += __shfl_xor(t[j], 2);
        }

        // x_k = y_k - sum_j C[j][k] * r_j   (this lane's 16 k's)
        #pragma unroll
        for (int j = 0; j < 16; ++j) {
            const float rj = t[j];
            const float4 c0 = sC4[j * 16 + c * 4 + 0];
            const float4 c1 = sC4[j * 16 + c * 4 + 1];
            const float4 c2 = sC4[j * 16 + c * 4 + 2];
            const float4 c3 = sC4[j * 16 + c * 4 + 3];
            yv0.x = fmaf(-c0.x, rj, yv0.x);
            yv0.y = fmaf(-c0.y, rj, yv0.y);
            yv0.z = fmaf(-c0.z, rj, yv0.z);
            yv0.w = fmaf(-c0.w, rj, yv0.w);
            yv1.x = fmaf(-c1.x, rj, yv1.x);
            yv1.y = fmaf(-c1.y, rj, yv1.y);
            yv1.z = fmaf(-c1.z, rj, yv1.z);
            yv1.w = fmaf(-c1.w, rj, yv1.w);
            yv2.x = fmaf(-c2.x, rj, yv2.x);
            yv2.y = fmaf(-c2.y, rj, yv2.y);
            yv2.z = fmaf(-c2.z, rj, yv2.z);
            yv2.w = fmaf(-c2.w, rj, yv2.w);
            yv3.x = fmaf(-c3.x, rj, yv3.x);
            yv3.y = fmaf(-c3.y, rj, yv3.y);
            yv3.z = fmaf(-c3.z, rj, yv3.z);
            yv3.w = fmaf(-c3.w, rj, yv3.w);
        }

        float4* o4 = reinterpret_cast<float4*>(out) + row * 16 + c * 4;
        o4[0] = yv0; o4[1] = yv1; o4[2] = yv2; o4[3] = yv3;
    }
}

// ---------------------------------------------------------------------------
extern "C" void kernel_launch(void* const* d_in, const int* in_sizes, int n_in,
                              void* d_out, int out_size, void* d_ws, size_t ws_size,
                              hipStream_t stream) {
    const float* y = (const float*)d_in[0];   // (1048576, 64)
    const float* A = (const float*)d_in[1];   // (16, 64)
    const float* b = (const float*)d_in[2];   // (1048576, 16)
    float* out = (float*)d_out;               // (1048576, 64)
    float* GC  = (float*)d_ws;                // 1280 floats: G(256) + C(1024)

    precompute_kernel<<<1, 256, 0, stream>>>(A, GC);
    apply_kernel<<<GRID, 256, 0, stream>>>(y, b, A, GC, out);
}

// Round 3
// 202.343 us; speedup vs baseline: 1.6983x; 1.6983x over previous
//
#include <hip/hip_runtime.h>

#define BATCH   1048576
#define IN_DIM  64
#define OUT_DIM 16

// ---------------------------------------------------------------------------
// Kernel 1: G = (A A^T)^-1  (16x16), C = G*A (16x64), written to workspace.
// Single block, 256 threads. Gauss-Jordan with partial pivoting in LDS.
// (validated in rounds 1-2)
// ---------------------------------------------------------------------------
__global__ __launch_bounds__(256) void precompute_kernel(
    const float* __restrict__ A, float* __restrict__ GC)
{
    __shared__ float sA[16][64];
    __shared__ float M[16][32];   // [S | I]
    __shared__ float fac[16];
    __shared__ int piv;

    const int tid = threadIdx.x;

    for (int i = tid; i < 1024; i += 256) sA[i >> 6][i & 63] = A[i];
    __syncthreads();

    {
        const int i = tid >> 4, j = tid & 15;
        float s = 0.f;
        #pragma unroll
        for (int k = 0; k < 64; ++k) s = fmaf(sA[i][k], sA[j][k], s);
        M[i][j] = s;
        M[i][16 + j] = (i == j) ? 1.f : 0.f;
    }
    __syncthreads();

    for (int p = 0; p < 16; ++p) {
        if (tid == 0) {
            int best = p;
            float bv = fabsf(M[p][p]);
            for (int r = p + 1; r < 16; ++r) {
                float v = fabsf(M[r][p]);
                if (v > bv) { bv = v; best = r; }
            }
            piv = best;
        }
        __syncthreads();
        if (tid < 32) {
            const int pr = piv;
            if (pr != p) { float t = M[p][tid]; M[p][tid] = M[pr][tid]; M[pr][tid] = t; }
        }
        __syncthreads();
        const float pv = M[p][p];
        __syncthreads();
        if (tid < 32) M[p][tid] *= (1.0f / pv);
        __syncthreads();
        if (tid < 16) fac[tid] = M[tid][p];
        __syncthreads();
        for (int e = tid; e < 512; e += 256) {
            const int r = e >> 5, c = e & 31;
            if (r != p) M[r][c] = fmaf(-fac[r], M[p][c], M[r][c]);
        }
        __syncthreads();
    }

    // G -> GC[0:256)
    {
        const int i = tid >> 4, j = tid & 15;
        GC[tid] = M[i][16 + j];
    }
    // C = G*A -> GC[256:1280)
    for (int e = tid; e < 1024; e += 256) {
        const int i = e >> 6, k = e & 63;
        float s = 0.f;
        #pragma unroll
        for (int j = 0; j < 16; ++j) s = fmaf(M[i][16 + j], sA[j][k], s);
        GC[256 + e] = s;
    }
}

// ---------------------------------------------------------------------------
// Kernel 2: thread-per-row  x = y - C^T (A y - b).
// All matrix reads are wave-uniform ds_read_b128 broadcasts (8 insts/row on
// the LDS pipe). Register budget capped at 128 VGPR via launch_bounds so the
// fully-unrolled body cannot kill occupancy (round-2 lesson).
// ---------------------------------------------------------------------------
__global__ __launch_bounds__(256, 4) void apply_kernel(
    const float* __restrict__ y, const float* __restrict__ b,
    const float* __restrict__ A, const float* __restrict__ GC,
    float* __restrict__ out)
{
    __shared__ float4 sA4[256];   // A  row-major, float4: index j*16 + q
    __shared__ float4 sC4[256];   // C  row-major, float4

    const int tid = threadIdx.x;
    const size_t row = (size_t)blockIdx.x * 256 + tid;
    const float4* y4 = reinterpret_cast<const float4*>(y) + row * 16;
    const float4* b4 = reinterpret_cast<const float4*>(b) + row * 4;

    // Issue global loads BEFORE the staging barrier: HBM latency hides there.
    float4 yv[16];
    #pragma unroll
    for (int q = 0; q < 16; ++q) yv[q] = y4[q];
    float t[16];
    #pragma unroll
    for (int q = 0; q < 4; ++q) {
        const float4 bv = b4[q];
        t[4*q+0] = -bv.x; t[4*q+1] = -bv.y; t[4*q+2] = -bv.z; t[4*q+3] = -bv.w;
    }

    sA4[tid] = reinterpret_cast<const float4*>(A)[tid];
    sC4[tid] = reinterpret_cast<const float4*>(GC + 256)[tid];
    __syncthreads();

    // t[j] = A[j]·y - b[j]
    #pragma unroll
    for (int j = 0; j < 16; ++j) {
        float acc = t[j];
        #pragma unroll
        for (int q = 0; q < 16; ++q) {
            const float4 a = sA4[j * 16 + q];
            acc = fmaf(a.x, yv[q].x, acc);
            acc = fmaf(a.y, yv[q].y, acc);
            acc = fmaf(a.z, yv[q].z, acc);
            acc = fmaf(a.w, yv[q].w, acc);
        }
        t[j] = acc;
    }

    // x = y - sum_j t[j] * C[j]
    #pragma unroll
    for (int j = 0; j < 16; ++j) {
        const float rj = t[j];
        #pragma unroll
        for (int q = 0; q < 16; ++q) {
            const float4 c = sC4[j * 16 + q];
            yv[q].x = fmaf(-c.x, rj, yv[q].x);
            yv[q].y = fmaf(-c.y, rj, yv[q].y);
            yv[q].z = fmaf(-c.z, rj, yv[q].z);
            yv[q].w = fmaf(-c.w, rj, yv[q].w);
        }
    }

    float4* o4 = reinterpret_cast<float4*>(out) + row * 16;
    #pragma unroll
    for (int q = 0; q < 16; ++q) o4[q] = yv[q];
}

// ---------------------------------------------------------------------------
extern "C" void kernel_launch(void* const* d_in, const int* in_sizes, int n_in,
                              void* d_out, int out_size, void* d_ws, size_t ws_size,
                              hipStream_t stream) {
    const float* y = (const float*)d_in[0];   // (1048576, 64)
    const float* A = (const float*)d_in[1];   // (16, 64)
    const float* b = (const float*)d_in[2];   // (1048576, 16)
    float* out = (float*)d_out;               // (1048576, 64)
    float* GC  = (float*)d_ws;                // 1280 floats: G(256) + C(1024)

    precompute_kernel<<<1, 256, 0, stream>>>(A, GC);
    apply_kernel<<<BATCH / 256, 256, 0, stream>>>(y, b, A, GC, out);
}

// Round 4
// 178.719 us; speedup vs baseline: 1.9227x; 1.1322x over previous
//
#include <hip/hip_runtime.h>

#define BATCH   1048576
#define IN_DIM  64
#define OUT_DIM 16

// ---------------------------------------------------------------------------
// Kernel 1: G = (A A^T)^-1  (16x16), C = G*A (16x64), written to workspace.
// Single block, 256 threads. Gauss-Jordan with partial pivoting in LDS.
// (validated in rounds 1-3)
// ---------------------------------------------------------------------------
__global__ __launch_bounds__(256) void precompute_kernel(
    const float* __restrict__ A, float* __restrict__ GC)
{
    __shared__ float sA[16][64];
    __shared__ float M[16][32];   // [S | I]
    __shared__ float fac[16];
    __shared__ int piv;

    const int tid = threadIdx.x;

    for (int i = tid; i < 1024; i += 256) sA[i >> 6][i & 63] = A[i];
    __syncthreads();

    {
        const int i = tid >> 4, j = tid & 15;
        float s = 0.f;
        #pragma unroll
        for (int k = 0; k < 64; ++k) s = fmaf(sA[i][k], sA[j][k], s);
        M[i][j] = s;
        M[i][16 + j] = (i == j) ? 1.f : 0.f;
    }
    __syncthreads();

    for (int p = 0; p < 16; ++p) {
        if (tid == 0) {
            int best = p;
            float bv = fabsf(M[p][p]);
            for (int r = p + 1; r < 16; ++r) {
                float v = fabsf(M[r][p]);
                if (v > bv) { bv = v; best = r; }
            }
            piv = best;
        }
        __syncthreads();
        if (tid < 32) {
            const int pr = piv;
            if (pr != p) { float t = M[p][tid]; M[p][tid] = M[pr][tid]; M[pr][tid] = t; }
        }
        __syncthreads();
        const float pv = M[p][p];
        __syncthreads();
        if (tid < 32) M[p][tid] *= (1.0f / pv);
        __syncthreads();
        if (tid < 16) fac[tid] = M[tid][p];
        __syncthreads();
        for (int e = tid; e < 512; e += 256) {
            const int r = e >> 5, c = e & 31;
            if (r != p) M[r][c] = fmaf(-fac[r], M[p][c], M[r][c]);
        }
        __syncthreads();
    }

    // G -> GC[0:256)
    {
        const int i = tid >> 4, j = tid & 15;
        GC[tid] = M[i][16 + j];
    }
    // C = G*A -> GC[256:1280)
    for (int e = tid; e < 1024; e += 256) {
        const int i = e >> 6, k = e & 63;
        float s = 0.f;
        #pragma unroll
        for (int j = 0; j < 16; ++j) s = fmaf(M[i][16 + j], sA[j][k], s);
        GC[256 + e] = s;
    }
}

// ---------------------------------------------------------------------------
// Kernel 2: thread-per-row  x = y - C^T (A y - b).
// Matrices A and C are read with WAVE-UNIFORM addresses from global memory:
// the backend selects s_load into SGPRs (constant cache) and v_fmac_f32 takes
// the matrix element as its SGPR operand. Zero LDS instructions in the hot
// path (round-3 lesson: 512 broadcast ds_read_b128/thread was the serializer
// at ~16B/inst of useful bandwidth).
// ---------------------------------------------------------------------------
__global__ __launch_bounds__(256, 4) void apply_kernel(
    const float* __restrict__ y, const float* __restrict__ b,
    const float* __restrict__ A, const float* __restrict__ GC,
    float* __restrict__ out)
{
    const int tid = threadIdx.x;
    const size_t row = (size_t)blockIdx.x * 256 + tid;
    const float4* __restrict__ y4 = reinterpret_cast<const float4*>(y) + row * 16;
    const float4* __restrict__ b4 = reinterpret_cast<const float4*>(b) + row * 4;
    const float4* __restrict__ A4 = reinterpret_cast<const float4*>(A);        // uniform
    const float4* __restrict__ C4 = reinterpret_cast<const float4*>(GC + 256); // uniform

    // Per-row data (per-lane, coalesced dwordx4 loads).
    float4 yv[16];
    #pragma unroll
    for (int q = 0; q < 16; ++q) yv[q] = y4[q];

    float t[16];
    #pragma unroll
    for (int q = 0; q < 4; ++q) {
        const float4 bv = b4[q];
        t[4*q+0] = -bv.x; t[4*q+1] = -bv.y; t[4*q+2] = -bv.z; t[4*q+3] = -bv.w;
    }

    // t[j] = A[j]·y - b[j]   (matrix elements via scalar path)
    #pragma unroll
    for (int j = 0; j < 16; ++j) {
        float acc = t[j];
        #pragma unroll
        for (int q = 0; q < 16; ++q) {
            const float4 a = A4[j * 16 + q];
            acc = fmaf(a.x, yv[q].x, acc);
            acc = fmaf(a.y, yv[q].y, acc);
            acc = fmaf(a.z, yv[q].z, acc);
            acc = fmaf(a.w, yv[q].w, acc);
        }
        t[j] = acc;
    }

    // x = y - sum_j t[j] * C[j]
    #pragma unroll
    for (int j = 0; j < 16; ++j) {
        const float rj = t[j];
        #pragma unroll
        for (int q = 0; q < 16; ++q) {
            const float4 c = C4[j * 16 + q];
            yv[q].x = fmaf(-c.x, rj, yv[q].x);
            yv[q].y = fmaf(-c.y, rj, yv[q].y);
            yv[q].z = fmaf(-c.z, rj, yv[q].z);
            yv[q].w = fmaf(-c.w, rj, yv[q].w);
        }
    }

    float4* __restrict__ o4 = reinterpret_cast<float4*>(out) + row * 16;
    #pragma unroll
    for (int q = 0; q < 16; ++q) o4[q] = yv[q];
}

// ---------------------------------------------------------------------------
extern "C" void kernel_launch(void* const* d_in, const int* in_sizes, int n_in,
                              void* d_out, int out_size, void* d_ws, size_t ws_size,
                              hipStream_t stream) {
    const float* y = (const float*)d_in[0];   // (1048576, 64)
    const float* A = (const float*)d_in[1];   // (16, 64)
    const float* b = (const float*)d_in[2];   // (1048576, 16)
    float* out = (float*)d_out;               // (1048576, 64)
    float* GC  = (float*)d_ws;                // 1280 floats: G(256) + C(1024)

    precompute_kernel<<<1, 256, 0, stream>>>(A, GC);
    apply_kernel<<<BATCH / 256, 256, 0, stream>>>(y, b, A, GC, out);
}